// Round 11
// baseline (245.680 us; speedup 1.0000x reference)
//
#include <hip/hip_runtime.h>
#include <hip/hip_bf16.h>

typedef __bf16 bf16_t;
typedef __bf16 bf16x4 __attribute__((ext_vector_type(4)));
typedef __bf16 bf16x8 __attribute__((ext_vector_type(8)));
typedef float f32x4 __attribute__((ext_vector_type(4)));
typedef float f32x16 __attribute__((ext_vector_type(16)));

#define MFMA16(a, b, c) __builtin_amdgcn_mfma_f32_16x16x32_bf16(a, b, c, 0, 0, 0)
#define MFMA32(a, b, c) __builtin_amdgcn_mfma_f32_32x32x16_bf16(a, b, c, 0, 0, 0)

// async 16B global->LDS. lds ptr wave-uniform; lane writes ldsbase+lane*16;
// GLOBAL src is per-lane (enables pre-swizzled source).
__device__ __forceinline__ void gld16(const bf16_t* g, bf16_t* l) {
  __builtin_amdgcn_global_load_lds(
      (const __attribute__((address_space(1))) unsigned int*)(const void*)g,
      (__attribute__((address_space(3))) unsigned int*)(void*)l, 16, 0, 0);
}

// Δ8-row XOR swizzle (element units, 8-elem granularity), both-sides
// involution on write and read.
__device__ __forceinline__ int swz8(int row) { return ((row >> 3) & 3) << 3; }

// ---------------------------------------------------------------------------
// merged f32 -> bf16 convert for all three tensors (one launch)
// ---------------------------------------------------------------------------
__global__ __launch_bounds__(256) void cvt3_f32_bf16(
    const float* __restrict__ s0, bf16_t* __restrict__ d0, long long n0,
    const float* __restrict__ s1, bf16_t* __restrict__ d1, long long n1,
    const float* __restrict__ s2, bf16_t* __restrict__ d2, long long n2) {
  const long long t0 = ((long long)blockIdx.x * 256 + threadIdx.x) * 8;
  const long long stride = (long long)gridDim.x * 256 * 8;
#pragma unroll 1
  for (int seg = 0; seg < 3; ++seg) {
    const float* s = (seg == 0) ? s0 : (seg == 1) ? s1 : s2;
    bf16_t* d = (seg == 0) ? d0 : (seg == 1) ? d1 : d2;
    const long long n = (seg == 0) ? n0 : (seg == 1) ? n1 : n2;
    if (!d) continue;
    for (long long i = t0; i < n; i += stride) {
      f32x4 a = *(const f32x4*)(s + i);
      f32x4 b = *(const f32x4*)(s + i + 4);
      bf16x8 r;
#pragma unroll
      for (int e = 0; e < 4; ++e) {
        r[e] = (bf16_t)a[e];
        r[4 + e] = (bf16_t)b[e];
      }
      *(bf16x8*)(d + i) = r;
    }
  }
}

// ---------------------------------------------------------------------------
// GEMM (r9 config — best measured): 128x128 tile, 4 waves, BK=64 single-
// buffer, T2 pre-swizzled-source staging + swizzled reads, chunked XCD
// swizzle, __launch_bounds__(256,3). UNCHANGED.
// ---------------------------------------------------------------------------
template <bool WF32, typename TC, bool BIAS>
__global__ __launch_bounds__(256, 3) void gemm_async(
    const bf16_t* __restrict__ A, int lda, const void* __restrict__ Wv,
    const float* __restrict__ bias, TC* __restrict__ C, int ldc,
    int M, int N, int K) {
  __shared__ bf16_t As[128 * 64];
  __shared__ bf16_t Bs[128 * 64];

  const int tid = threadIdx.x;
  const int i = tid & 63;
  const int w = tid >> 6;
  const int l16 = tid & 15;
  const int quad = (tid >> 4) & 3;
  const int wm = w & 1;
  const int wn = w >> 1;

  const int nwg = gridDim.x * gridDim.y;
  int wg = blockIdx.y * gridDim.x + blockIdx.x;
  if ((nwg & 7) == 0) wg = (wg & 7) * (nwg >> 3) + (wg >> 3);
  const int m0 = (wg / gridDim.x) * 128;
  const int n0 = (wg % gridDim.x) * 128;

  const int srw = i >> 3;
  const int ssl = ((i & 7) ^ srw) << 3;
  const bf16_t* ag = A + (size_t)(m0 + w * 32 + srw) * lda + ssl;

  const bf16_t* bg = nullptr;
  const float* wfg = nullptr;
  int bsrow = 0, bchunk = 0;
  if (!WF32) {
    bg = (const bf16_t*)Wv + (size_t)(n0 + w * 32 + srw) * K + ssl;
  } else {
    bsrow = tid >> 1;
    bchunk = tid & 1;
    wfg = (const float*)Wv + (size_t)(n0 + bsrow) * K + bchunk * 32;
  }

  f32x4 acc[4][4] = {};

  for (int kt = 0; kt < (K >> 6); ++kt) {
    if (kt) __syncthreads();
#pragma unroll
    for (int g = 0; g < 4; ++g)
      gld16(ag + (size_t)(g * 8) * lda + kt * 64, &As[(w * 32 + g * 8) * 64]);
    if (!WF32) {
#pragma unroll
      for (int g = 0; g < 4; ++g)
        gld16(bg + (size_t)(g * 8) * K + kt * 64, &Bs[(w * 32 + g * 8) * 64]);
    } else {
#pragma unroll
      for (int j = 0; j < 4; ++j) {
        f32x4 a = *(const f32x4*)(wfg + kt * 64 + j * 8);
        f32x4 b = *(const f32x4*)(wfg + kt * 64 + j * 8 + 4);
        bf16x8 r;
#pragma unroll
        for (int e = 0; e < 4; ++e) {
          r[e] = (bf16_t)a[e];
          r[4 + e] = (bf16_t)b[e];
        }
        const int slot = (bchunk * 4 + j) ^ (bsrow & 7);
        *(bf16x8*)&Bs[bsrow * 64 + slot * 8] = r;
      }
    }
    __syncthreads();

#pragma unroll
    for (int ks = 0; ks < 2; ++ks) {
      bf16x8 af[4], bfr[4];
#pragma unroll
      for (int t = 0; t < 4; ++t) {
        const int ar = wm * 64 + t * 16 + l16;
        const int br = wn * 64 + t * 16 + l16;
        const int slot = ((ks * 4 + quad) ^ (l16 & 7)) * 8;
        af[t] = *(const bf16x8*)&As[ar * 64 + slot];
        bfr[t] = *(const bf16x8*)&Bs[br * 64 + slot];
      }
      __builtin_amdgcn_s_setprio(1);
#pragma unroll
      for (int mi = 0; mi < 4; ++mi)
#pragma unroll
        for (int ni = 0; ni < 4; ++ni)
          acc[mi][ni] = MFMA16(af[mi], bfr[ni], acc[mi][ni]);
      __builtin_amdgcn_s_setprio(0);
    }
  }

#pragma unroll
  for (int ni = 0; ni < 4; ++ni) {
    const int col = n0 + wn * 64 + ni * 16 + l16;
    const float bv = BIAS ? bias[col] : 0.0f;
#pragma unroll
    for (int mi = 0; mi < 4; ++mi) {
      const int row = m0 + wm * 64 + mi * 16 + quad * 4;
#pragma unroll
      for (int r = 0; r < 4; ++r)
        C[(size_t)(row + r) * ldc + col] = (TC)(acc[mi][ni][r] + bv);
    }
  }
}

// ---------------------------------------------------------------------------
// Flash attention (causal), qkv interleaved [B*T, 3C] bf16. Output overwrites
// the Q slot in place.
//
// v8 (this round): r10's 32x32 structure with the PV operand-order BUG fixed.
// r10 computed MFMA32(P^T_frag, V_frag) = O (col=d) but the epilogue assumes
// O^T (col = own q-row) -> every 32x32 block written (q,d)-transposed ->
// absmax 7.39. Fix: MFMA32(V^T_frag, P^T_frag) = O^T[d][q], col=q=l31.
// QK^T (MFMA32(K,Q) = S^T, col=q) was already consistent with the verified
// C/D mapping row=(reg&3)+8*(reg>>2)+4*(lane>>5), col=lane&31 [m74/m101].
// k-ordering inside each MFMA window cancels between A and B (both built
// from consecutive-8 loads with the same assumed order).
// ---------------------------------------------------------------------------
__global__ __launch_bounds__(256, 2) void attn_mfma(bf16_t* __restrict__ qkv) {
  constexpr int T = 2048, C3 = 3072, C = 1024;
  __shared__ bf16_t Ks[64 * 72];  // [token][d^swz]
  __shared__ bf16_t Vt[64 * 72];  // [d][token^swz]

  const int tid = threadIdx.x;
  const int wave = tid >> 6;   // 0..3
  const int lane = tid & 63;
  const int l31 = lane & 31;
  const int hi = lane >> 5;    // 0..1
  const int p = blockIdx.x;    // 0..7 -> strips p and 15-p
  const int b = blockIdx.y >> 4;
  const int h = blockIdx.y & 15;
  bf16_t* base = qkv + (size_t)b * T * C3;

  const float QSCALE = 0.125f * 1.44269504088896340736f;

  // staging: waves 0-1 stage K (token=tid>>1, 32 d at (tid&1)*32);
  // waves 2-3 stage V transposed (token=lane, 32 d at (wave-2)*32).
  const int ktok = tid >> 1;
  const int kd0 = (tid & 1) * 32;
  const int vtok = lane;
  const int vd0 = (wave - 2) * 32;

  bf16x8 st0, st1, st2, st3;

  for (int s = 0; s < 2; ++s) {
    const int qt = (s == 0) ? p : 15 - p;
    const int Q0 = qt * 128;
    const int qlo = Q0 + wave * 32;
    const int jmax = Q0 + 64;

    // Q as B-frag: lane holds Q[qlo+l31][h*64 + kd*16 + hi*8 + e] * QSCALE
    bf16x8 qf[4];
    {
      const bf16_t* qp = base + (size_t)(qlo + l31) * C3 + h * 64 + hi * 8;
#pragma unroll
      for (int kd = 0; kd < 4; ++kd) {
        bf16x8 a = *(const bf16x8*)(qp + kd * 16);
#pragma unroll
        for (int e = 0; e < 8; ++e) a[e] = (bf16_t)((float)a[e] * QSCALE);
        qf[kd] = a;
      }
    }

    f32x16 Of0 = {}, Of1 = {};   // O^T d-blocks 0-31 / 32-63, col = own q
    float mrow = -1e30f, lrow = 0.f;

    // prologue: tile-0 loads into regs (T14 split)
    if (wave < 2) {
      const bf16_t* kp = base + (size_t)ktok * C3 + C + h * 64 + kd0;
      st0 = *(const bf16x8*)kp;
      st1 = *(const bf16x8*)(kp + 8);
      st2 = *(const bf16x8*)(kp + 16);
      st3 = *(const bf16x8*)(kp + 24);
    } else {
      const bf16_t* vp = base + (size_t)vtok * C3 + 2 * C + h * 64 + vd0;
      st0 = *(const bf16x8*)vp;
      st1 = *(const bf16x8*)(vp + 8);
      st2 = *(const bf16x8*)(vp + 16);
      st3 = *(const bf16x8*)(vp + 24);
    }

    for (int j0 = 0; j0 <= jmax; j0 += 64) {
      __syncthreads();  // previous tile's readers done
      if (wave < 2) {
        *(bf16x8*)&Ks[ktok * 72 + ((kd0 + 0) ^ swz8(ktok))] = st0;
        *(bf16x8*)&Ks[ktok * 72 + ((kd0 + 8) ^ swz8(ktok))] = st1;
        *(bf16x8*)&Ks[ktok * 72 + ((kd0 + 16) ^ swz8(ktok))] = st2;
        *(bf16x8*)&Ks[ktok * 72 + ((kd0 + 24) ^ swz8(ktok))] = st3;
      } else {
#pragma unroll
        for (int e = 0; e < 8; ++e) {
          int d0 = vd0 + e, d1 = vd0 + 8 + e, d2 = vd0 + 16 + e,
              d3 = vd0 + 24 + e;
          Vt[d0 * 72 + (vtok ^ swz8(d0))] = st0[e];
          Vt[d1 * 72 + (vtok ^ swz8(d1))] = st1[e];
          Vt[d2 * 72 + (vtok ^ swz8(d2))] = st2[e];
          Vt[d3 * 72 + (vtok ^ swz8(d3))] = st3[e];
        }
      }
      // issue next tile's loads; consumed next iteration via reg dep
      if (j0 + 64 <= jmax) {
        const int jn = j0 + 64;
        if (wave < 2) {
          const bf16_t* kp = base + (size_t)(jn + ktok) * C3 + C + h * 64 + kd0;
          st0 = *(const bf16x8*)kp;
          st1 = *(const bf16x8*)(kp + 8);
          st2 = *(const bf16x8*)(kp + 16);
          st3 = *(const bf16x8*)(kp + 24);
        } else {
          const bf16_t* vp =
              base + (size_t)(jn + vtok) * C3 + 2 * C + h * 64 + vd0;
          st0 = *(const bf16x8*)vp;
          st1 = *(const bf16x8*)(vp + 8);
          st2 = *(const bf16x8*)(vp + 16);
          st3 = *(const bf16x8*)(vp + 24);
        }
      }
      __syncthreads();

      if (qlo + 31 < j0) continue;  // wave fully masked (barriers done above)

      // S^T = mfma32(K, Q): Sa0 keys j0+0..31, Sa1 keys j0+32..63; col = q
      f32x16 Sa0 = {}, Sa1 = {};
      __builtin_amdgcn_s_setprio(1);
#pragma unroll
      for (int kd = 0; kd < 4; ++kd) {
        const int c = (kd * 16 + hi * 8);
        bf16x8 k0 = *(const bf16x8*)&Ks[l31 * 72 + (c ^ swz8(l31))];
        bf16x8 k1 = *(const bf16x8*)&Ks[(32 + l31) * 72 + (c ^ swz8(32 + l31))];
        Sa0 = MFMA32(k0, qf[kd], Sa0);
        Sa1 = MFMA32(k1, qf[kd], Sa1);
      }
      __builtin_amdgcn_s_setprio(0);

      // causal mask: only diagonal-overlap tiles (wave-uniform skip)
      if (j0 + 63 > qlo) {
        const int qrow = qlo + l31;
#pragma unroll
        for (int g = 0; g < 4; ++g)
#pragma unroll
          for (int j = 0; j < 4; ++j) {
            const int key0 = j0 + 8 * g + 4 * hi + j;
            if (key0 > qrow) Sa0[4 * g + j] = -1e30f;
            if (key0 + 32 > qrow) Sa1[4 * g + j] = -1e30f;
          }
      }

      // row max: in-lane over 32 + one cross-hi exchange
      float v = -1e30f;
#pragma unroll
      for (int r2 = 0; r2 < 16; ++r2) {
        v = fmaxf(v, Sa0[r2]);
        v = fmaxf(v, Sa1[r2]);
      }
      v = fmaxf(v, __shfl_xor(v, 32));

      // exact defer-skip; alpha is lane-local (no broadcast)
      if (__any(v > mrow)) {
        const float mnew = fmaxf(mrow, v);
        const float alpha = __builtin_amdgcn_exp2f(mrow - mnew);
        mrow = mnew;
        lrow *= alpha;
#pragma unroll
        for (int r2 = 0; r2 < 16; ++r2) {
          Of0[r2] *= alpha;
          Of1[r2] *= alpha;
        }
      }

      // P = exp2(S-m), packed per reg-quad g: keys kb*32 + 8g + 4hi + j
      float rs = 0.f;
      bf16x4 pk0[4], pk1[4];
#pragma unroll
      for (int g = 0; g < 4; ++g) {
        bf16x4 a4, b4;
#pragma unroll
        for (int j = 0; j < 4; ++j) {
          float p0 = __builtin_amdgcn_exp2f(Sa0[4 * g + j] - mrow);
          float p1 = __builtin_amdgcn_exp2f(Sa1[4 * g + j] - mrow);
          rs += p0 + p1;
          a4[j] = (bf16_t)p0;
          b4[j] = (bf16_t)p1;
        }
        pk0[g] = a4;
        pk1[g] = b4;
      }
      rs += __shfl_xor(rs, 32);
      lrow += rs;

      // P^T B-frags via register exchange: pfr[kdt] holds
      // P[q=l31][key = kdt*16 + hi*8 + e].
      union U {
        bf16x4 v;
        long long ll;
      };
      bf16x8 pfr[4];
#pragma unroll
      for (int kb = 0; kb < 2; ++kb) {
        const bf16x4 q0 = kb ? pk1[0] : pk0[0];
        const bf16x4 q1 = kb ? pk1[1] : pk0[1];
        const bf16x4 q2 = kb ? pk1[2] : pk0[2];
        const bf16x4 q3 = kb ? pk1[3] : pk0[3];
        U ua;
        ua.v = hi ? q0 : q1;             // hi0 sends g1, hi1 sends g0
        U ra;
        ra.ll = __shfl_xor(ua.ll, 32);   // hi0 recv partner g0; hi1 recv g1
        U ub;
        ub.v = hi ? q2 : q3;             // hi0 sends g3, hi1 sends g2
        U rb;
        rb.ll = __shfl_xor(ub.ll, 32);   // hi0 recv partner g2; hi1 recv g3
        const bf16x4 lo0 = hi ? ra.v : q0;
        const bf16x4 hi0v = hi ? q1 : ra.v;
        const bf16x4 lo1 = hi ? rb.v : q2;
        const bf16x4 hi1v = hi ? q3 : rb.v;
        bf16x8 f0, f1;
#pragma unroll
        for (int j = 0; j < 4; ++j) {
          f0[j] = lo0[j];
          f0[4 + j] = hi0v[j];
          f1[j] = lo1[j];
          f1[4 + j] = hi1v[j];
        }
        pfr[kb * 2 + 0] = f0;
        pfr[kb * 2 + 1] = f1;
      }

      // PV: O^T += mfma32(V^T, P^T) — A=V^T (rows=d), B=P^T (cols=q).
      // (r10 had these swapped -> transposed output.)
      __builtin_amdgcn_s_setprio(1);
#pragma unroll
      for (int kdt = 0; kdt < 4; ++kdt) {
        const int c = (kdt * 16 + hi * 8);
        bf16x8 v0 = *(const bf16x8*)&Vt[l31 * 72 + (c ^ swz8(l31))];
        bf16x8 v1 = *(const bf16x8*)&Vt[(32 + l31) * 72 + (c ^ swz8(32 + l31))];
        Of0 = MFMA32(v0, pfr[kdt], Of0);
        Of1 = MFMA32(v1, pfr[kdt], Of1);
      }
      __builtin_amdgcn_s_setprio(0);
    }

    // epilogue: O^T lane holds d-chunks {8g+4hi..+3} of its own q-row;
    // 8B-contiguous stores, both hi lanes cover complementary d.
    const float inv = 1.0f / lrow;
    bf16_t* op = base + (size_t)(qlo + l31) * C3 + h * 64;
#pragma unroll
    for (int g = 0; g < 4; ++g) {
      bf16x4 o0, o1;
#pragma unroll
      for (int j = 0; j < 4; ++j) {
        o0[j] = (bf16_t)(Of0[4 * g + j] * inv);
        o1[j] = (bf16_t)(Of1[4 * g + j] * inv);
      }
      *(bf16x4*)&op[8 * g + 4 * hi] = o0;
      *(bf16x4*)&op[32 + 8 * g + 4 * hi] = o1;
    }
  }
}

// ---------------------------------------------------------------------------
// I/O contract (R8 probe): ALL inputs f32; output f32.
// ---------------------------------------------------------------------------
extern "C" void kernel_launch(void* const* d_in, const int* in_sizes, int n_in,
                              void* d_out, int out_size, void* d_ws,
                              size_t ws_size, hipStream_t stream) {
  constexpr int B = 4, T = 2048, C = 1024;
  constexpr int M = B * T;  // 8192

  const float* x = (const float*)d_in[0];
  const float* w_qkv = (const float*)d_in[1];
  const float* w_out = (const float*)d_in[2];
  const float* b_out = (const float*)d_in[3];
  for (int i = 0; i < n_in; ++i) {
    const long long s = in_sizes[i];
    if (s == (long long)M * C) x = (const float*)d_in[i];
    else if (s == (long long)3 * C * C) w_qkv = (const float*)d_in[i];
    else if (s == (long long)C * C) w_out = (const float*)d_in[i];
    else if (s == C) b_out = (const float*)d_in[i];
  }

  bf16_t* xb = (bf16_t*)d_out;                    // 16 MB
  bf16_t* wqb = xb + (size_t)M * C;               // 6 MB
  bf16_t* qkv = (bf16_t*)d_ws;                    // 48 MB
  bf16_t* wob = qkv + (size_t)M * 3 * C;          // +2 MB (guarded)
  const bool ws_ok =
      ws_size >= (size_t)M * 3 * C * 2 + (size_t)C * C * 2;

  cvt3_f32_bf16<<<1024, 256, 0, stream>>>(
      x, xb, (long long)M * C, w_qkv, wqb, 3LL * C * C, w_out,
      ws_ok ? wob : nullptr, (long long)C * C);

  // fused QKV: [M,3C] = xb @ wqb^T
  gemm_async<false, bf16_t, false>
      <<<dim3(3 * C / 128, M / 128), 256, 0, stream>>>(
          xb, C, wqb, nullptr, qkv, 3 * C, M, 3 * C, C);

  // attention in place (Q slot of qkv); pairing grid, 4-wave 32x32 blocks
  attn_mfma<<<dim3(8, B * 16), 256, 0, stream>>>(qkv);

  // out = att @ w_out^T + b_out -> f32 d_out
  if (ws_ok)
    gemm_async<false, float, true><<<dim3(C / 128, M / 128), 256, 0, stream>>>(
        qkv, 3 * C, wob, b_out, (float*)d_out, C, M, C, C);
  else
    gemm_async<true, float, true><<<dim3(C / 128, M / 128), 256, 0, stream>>>(
        qkv, 3 * C, w_out, b_out, (float*)d_out, C, M, C, C);
}

// Round 12
// 239.171 us; speedup vs baseline: 1.0272x; 1.0272x over previous
//
#include <hip/hip_runtime.h>
#include <hip/hip_bf16.h>

typedef __bf16 bf16_t;
typedef __bf16 bf16x4 __attribute__((ext_vector_type(4)));
typedef __bf16 bf16x8 __attribute__((ext_vector_type(8)));
typedef float f32x4 __attribute__((ext_vector_type(4)));
typedef float f32x16 __attribute__((ext_vector_type(16)));

#define MFMA16(a, b, c) __builtin_amdgcn_mfma_f32_16x16x32_bf16(a, b, c, 0, 0, 0)
#define MFMA32(a, b, c) __builtin_amdgcn_mfma_f32_32x32x16_bf16(a, b, c, 0, 0, 0)

// async 16B global->LDS. lds ptr wave-uniform; lane writes ldsbase+lane*16;
// GLOBAL src is per-lane (enables pre-swizzled source).
__device__ __forceinline__ void gld16(const bf16_t* g, bf16_t* l) {
  __builtin_amdgcn_global_load_lds(
      (const __attribute__((address_space(1))) unsigned int*)(const void*)g,
      (__attribute__((address_space(3))) unsigned int*)(void*)l, 16, 0, 0);
}

// Δ8-row XOR swizzle (element units, 8-elem granularity), both-sides
// involution on write and read.
__device__ __forceinline__ int swz8(int row) { return ((row >> 3) & 3) << 3; }

// ---------------------------------------------------------------------------
// merged f32 -> bf16 convert for all three tensors (one launch)
// ---------------------------------------------------------------------------
__global__ __launch_bounds__(256) void cvt3_f32_bf16(
    const float* __restrict__ s0, bf16_t* __restrict__ d0, long long n0,
    const float* __restrict__ s1, bf16_t* __restrict__ d1, long long n1,
    const float* __restrict__ s2, bf16_t* __restrict__ d2, long long n2) {
  const long long t0 = ((long long)blockIdx.x * 256 + threadIdx.x) * 8;
  const long long stride = (long long)gridDim.x * 256 * 8;
#pragma unroll 1
  for (int seg = 0; seg < 3; ++seg) {
    const float* s = (seg == 0) ? s0 : (seg == 1) ? s1 : s2;
    bf16_t* d = (seg == 0) ? d0 : (seg == 1) ? d1 : d2;
    const long long n = (seg == 0) ? n0 : (seg == 1) ? n1 : n2;
    if (!d) continue;
    for (long long i = t0; i < n; i += stride) {
      f32x4 a = *(const f32x4*)(s + i);
      f32x4 b = *(const f32x4*)(s + i + 4);
      bf16x8 r;
#pragma unroll
      for (int e = 0; e < 4; ++e) {
        r[e] = (bf16_t)a[e];
        r[4 + e] = (bf16_t)b[e];
      }
      *(bf16x8*)(d + i) = r;
    }
  }
}

// ---------------------------------------------------------------------------
// GEMM (r9 config — best measured): 128x128 tile, 4 waves, BK=64 single-
// buffer, T2 pre-swizzled-source staging + swizzled reads, chunked XCD
// swizzle, __launch_bounds__(256,3). UNCHANGED.
// ---------------------------------------------------------------------------
template <bool WF32, typename TC, bool BIAS>
__global__ __launch_bounds__(256, 3) void gemm_async(
    const bf16_t* __restrict__ A, int lda, const void* __restrict__ Wv,
    const float* __restrict__ bias, TC* __restrict__ C, int ldc,
    int M, int N, int K) {
  __shared__ bf16_t As[128 * 64];
  __shared__ bf16_t Bs[128 * 64];

  const int tid = threadIdx.x;
  const int i = tid & 63;
  const int w = tid >> 6;
  const int l16 = tid & 15;
  const int quad = (tid >> 4) & 3;
  const int wm = w & 1;
  const int wn = w >> 1;

  const int nwg = gridDim.x * gridDim.y;
  int wg = blockIdx.y * gridDim.x + blockIdx.x;
  if ((nwg & 7) == 0) wg = (wg & 7) * (nwg >> 3) + (wg >> 3);
  const int m0 = (wg / gridDim.x) * 128;
  const int n0 = (wg % gridDim.x) * 128;

  const int srw = i >> 3;
  const int ssl = ((i & 7) ^ srw) << 3;
  const bf16_t* ag = A + (size_t)(m0 + w * 32 + srw) * lda + ssl;

  const bf16_t* bg = nullptr;
  const float* wfg = nullptr;
  int bsrow = 0, bchunk = 0;
  if (!WF32) {
    bg = (const bf16_t*)Wv + (size_t)(n0 + w * 32 + srw) * K + ssl;
  } else {
    bsrow = tid >> 1;
    bchunk = tid & 1;
    wfg = (const float*)Wv + (size_t)(n0 + bsrow) * K + bchunk * 32;
  }

  f32x4 acc[4][4] = {};

  for (int kt = 0; kt < (K >> 6); ++kt) {
    if (kt) __syncthreads();
#pragma unroll
    for (int g = 0; g < 4; ++g)
      gld16(ag + (size_t)(g * 8) * lda + kt * 64, &As[(w * 32 + g * 8) * 64]);
    if (!WF32) {
#pragma unroll
      for (int g = 0; g < 4; ++g)
        gld16(bg + (size_t)(g * 8) * K + kt * 64, &Bs[(w * 32 + g * 8) * 64]);
    } else {
#pragma unroll
      for (int j = 0; j < 4; ++j) {
        f32x4 a = *(const f32x4*)(wfg + kt * 64 + j * 8);
        f32x4 b = *(const f32x4*)(wfg + kt * 64 + j * 8 + 4);
        bf16x8 r;
#pragma unroll
        for (int e = 0; e < 4; ++e) {
          r[e] = (bf16_t)a[e];
          r[4 + e] = (bf16_t)b[e];
        }
        const int slot = (bchunk * 4 + j) ^ (bsrow & 7);
        *(bf16x8*)&Bs[bsrow * 64 + slot * 8] = r;
      }
    }
    __syncthreads();

#pragma unroll
    for (int ks = 0; ks < 2; ++ks) {
      bf16x8 af[4], bfr[4];
#pragma unroll
      for (int t = 0; t < 4; ++t) {
        const int ar = wm * 64 + t * 16 + l16;
        const int br = wn * 64 + t * 16 + l16;
        const int slot = ((ks * 4 + quad) ^ (l16 & 7)) * 8;
        af[t] = *(const bf16x8*)&As[ar * 64 + slot];
        bfr[t] = *(const bf16x8*)&Bs[br * 64 + slot];
      }
      __builtin_amdgcn_s_setprio(1);
#pragma unroll
      for (int mi = 0; mi < 4; ++mi)
#pragma unroll
        for (int ni = 0; ni < 4; ++ni)
          acc[mi][ni] = MFMA16(af[mi], bfr[ni], acc[mi][ni]);
      __builtin_amdgcn_s_setprio(0);
    }
  }

#pragma unroll
  for (int ni = 0; ni < 4; ++ni) {
    const int col = n0 + wn * 64 + ni * 16 + l16;
    const float bv = BIAS ? bias[col] : 0.0f;
#pragma unroll
    for (int mi = 0; mi < 4; ++mi) {
      const int row = m0 + wm * 64 + mi * 16 + quad * 4;
#pragma unroll
      for (int r = 0; r < 4; ++r)
        C[(size_t)(row + r) * ldc + col] = (TC)(acc[mi][ni][r] + bv);
    }
  }
}

// ---------------------------------------------------------------------------
// Flash attention (causal), qkv interleaved [B*T, 3C] bf16. Output overwrites
// the Q slot in place.
//
// v9 (this round): OCCUPANCY for the 32x32 structure. r11 ran 512 blocks
// (2/CU = 8 waves/CU, Occ 19%) with every pipe <40% -> latency-bound with
// too few waves. One strip per block: grid (B*H=64, 16) = 1024 blocks ->
// 4 blocks/CU = 16 waves/CU. LDS 18.4KB x4 = 74KB, VGPR 84 -> fits.
// Strip balance via qt = (y<8) ? y : 23-y (r5 map; dynamic refill evens the
// rest). Arithmetic byte-identical to r11 (refcheck-passed).
// ---------------------------------------------------------------------------
__global__ __launch_bounds__(256, 2) void attn_mfma(bf16_t* __restrict__ qkv) {
  constexpr int T = 2048, C3 = 3072, C = 1024;
  __shared__ bf16_t Ks[64 * 72];  // [token][d^swz]
  __shared__ bf16_t Vt[64 * 72];  // [d][token^swz]

  const int tid = threadIdx.x;
  const int wave = tid >> 6;   // 0..3
  const int lane = tid & 63;
  const int l31 = lane & 31;
  const int hi = lane >> 5;    // 0..1
  const int bh = blockIdx.x;   // 0..63
  const int b = bh >> 4;
  const int h = bh & 15;
  const int y = blockIdx.y;    // 0..15
  const int qt = (y < 8) ? y : 23 - y;  // bijection, per-CU balanced
  bf16_t* base = qkv + (size_t)b * T * C3;

  const float QSCALE = 0.125f * 1.44269504088896340736f;

  // staging: waves 0-1 stage K (token=tid>>1, 32 d at (tid&1)*32);
  // waves 2-3 stage V transposed (token=lane, 32 d at (wave-2)*32).
  const int ktok = tid >> 1;
  const int kd0 = (tid & 1) * 32;
  const int vtok = lane;
  const int vd0 = (wave - 2) * 32;

  bf16x8 st0, st1, st2, st3;

  const int Q0 = qt * 128;
  const int qlo = Q0 + wave * 32;
  const int jmax = Q0 + 64;

  // Q as B-frag: lane holds Q[qlo+l31][h*64 + kd*16 + hi*8 + e] * QSCALE
  bf16x8 qf[4];
  {
    const bf16_t* qp = base + (size_t)(qlo + l31) * C3 + h * 64 + hi * 8;
#pragma unroll
    for (int kd = 0; kd < 4; ++kd) {
      bf16x8 a = *(const bf16x8*)(qp + kd * 16);
#pragma unroll
      for (int e = 0; e < 8; ++e) a[e] = (bf16_t)((float)a[e] * QSCALE);
      qf[kd] = a;
    }
  }

  f32x16 Of0 = {}, Of1 = {};   // O^T d-blocks 0-31 / 32-63, col = own q
  float mrow = -1e30f, lrow = 0.f;

  // prologue: tile-0 loads into regs (T14 split)
  if (wave < 2) {
    const bf16_t* kp = base + (size_t)ktok * C3 + C + h * 64 + kd0;
    st0 = *(const bf16x8*)kp;
    st1 = *(const bf16x8*)(kp + 8);
    st2 = *(const bf16x8*)(kp + 16);
    st3 = *(const bf16x8*)(kp + 24);
  } else {
    const bf16_t* vp = base + (size_t)vtok * C3 + 2 * C + h * 64 + vd0;
    st0 = *(const bf16x8*)vp;
    st1 = *(const bf16x8*)(vp + 8);
    st2 = *(const bf16x8*)(vp + 16);
    st3 = *(const bf16x8*)(vp + 24);
  }

  for (int j0 = 0; j0 <= jmax; j0 += 64) {
    __syncthreads();  // previous tile's readers done
    if (wave < 2) {
      *(bf16x8*)&Ks[ktok * 72 + ((kd0 + 0) ^ swz8(ktok))] = st0;
      *(bf16x8*)&Ks[ktok * 72 + ((kd0 + 8) ^ swz8(ktok))] = st1;
      *(bf16x8*)&Ks[ktok * 72 + ((kd0 + 16) ^ swz8(ktok))] = st2;
      *(bf16x8*)&Ks[ktok * 72 + ((kd0 + 24) ^ swz8(ktok))] = st3;
    } else {
#pragma unroll
      for (int e = 0; e < 8; ++e) {
        int d0 = vd0 + e, d1 = vd0 + 8 + e, d2 = vd0 + 16 + e,
            d3 = vd0 + 24 + e;
        Vt[d0 * 72 + (vtok ^ swz8(d0))] = st0[e];
        Vt[d1 * 72 + (vtok ^ swz8(d1))] = st1[e];
        Vt[d2 * 72 + (vtok ^ swz8(d2))] = st2[e];
        Vt[d3 * 72 + (vtok ^ swz8(d3))] = st3[e];
      }
    }
    // issue next tile's loads; consumed next iteration via reg dep
    if (j0 + 64 <= jmax) {
      const int jn = j0 + 64;
      if (wave < 2) {
        const bf16_t* kp = base + (size_t)(jn + ktok) * C3 + C + h * 64 + kd0;
        st0 = *(const bf16x8*)kp;
        st1 = *(const bf16x8*)(kp + 8);
        st2 = *(const bf16x8*)(kp + 16);
        st3 = *(const bf16x8*)(kp + 24);
      } else {
        const bf16_t* vp =
            base + (size_t)(jn + vtok) * C3 + 2 * C + h * 64 + vd0;
        st0 = *(const bf16x8*)vp;
        st1 = *(const bf16x8*)(vp + 8);
        st2 = *(const bf16x8*)(vp + 16);
        st3 = *(const bf16x8*)(vp + 24);
      }
    }
    __syncthreads();

    if (qlo + 31 < j0) continue;  // wave fully masked (barriers done above)

    // S^T = mfma32(K, Q): Sa0 keys j0+0..31, Sa1 keys j0+32..63; col = q
    f32x16 Sa0 = {}, Sa1 = {};
    __builtin_amdgcn_s_setprio(1);
#pragma unroll
    for (int kd = 0; kd < 4; ++kd) {
      const int c = (kd * 16 + hi * 8);
      bf16x8 k0 = *(const bf16x8*)&Ks[l31 * 72 + (c ^ swz8(l31))];
      bf16x8 k1 = *(const bf16x8*)&Ks[(32 + l31) * 72 + (c ^ swz8(32 + l31))];
      Sa0 = MFMA32(k0, qf[kd], Sa0);
      Sa1 = MFMA32(k1, qf[kd], Sa1);
    }
    __builtin_amdgcn_s_setprio(0);

    // causal mask: only diagonal-overlap tiles (wave-uniform skip)
    if (j0 + 63 > qlo) {
      const int qrow = qlo + l31;
#pragma unroll
      for (int g = 0; g < 4; ++g)
#pragma unroll
        for (int j = 0; j < 4; ++j) {
          const int key0 = j0 + 8 * g + 4 * hi + j;
          if (key0 > qrow) Sa0[4 * g + j] = -1e30f;
          if (key0 + 32 > qrow) Sa1[4 * g + j] = -1e30f;
        }
    }

    // row max: in-lane over 32 + one cross-hi exchange
    float v = -1e30f;
#pragma unroll
    for (int r2 = 0; r2 < 16; ++r2) {
      v = fmaxf(v, Sa0[r2]);
      v = fmaxf(v, Sa1[r2]);
    }
    v = fmaxf(v, __shfl_xor(v, 32));

    // exact defer-skip; alpha is lane-local (no broadcast)
    if (__any(v > mrow)) {
      const float mnew = fmaxf(mrow, v);
      const float alpha = __builtin_amdgcn_exp2f(mrow - mnew);
      mrow = mnew;
      lrow *= alpha;
#pragma unroll
      for (int r2 = 0; r2 < 16; ++r2) {
        Of0[r2] *= alpha;
        Of1[r2] *= alpha;
      }
    }

    // P = exp2(S-m), packed per reg-quad g: keys kb*32 + 8g + 4hi + j
    float rs = 0.f;
    bf16x4 pk0[4], pk1[4];
#pragma unroll
    for (int g = 0; g < 4; ++g) {
      bf16x4 a4, b4;
#pragma unroll
      for (int j = 0; j < 4; ++j) {
        float p0 = __builtin_amdgcn_exp2f(Sa0[4 * g + j] - mrow);
        float p1 = __builtin_amdgcn_exp2f(Sa1[4 * g + j] - mrow);
        rs += p0 + p1;
        a4[j] = (bf16_t)p0;
        b4[j] = (bf16_t)p1;
      }
      pk0[g] = a4;
      pk1[g] = b4;
    }
    rs += __shfl_xor(rs, 32);
    lrow += rs;

    // P^T B-frags via register exchange: pfr[kdt] holds
    // P[q=l31][key = kdt*16 + hi*8 + e].
    union U {
      bf16x4 v;
      long long ll;
    };
    bf16x8 pfr[4];
#pragma unroll
    for (int kb = 0; kb < 2; ++kb) {
      const bf16x4 q0 = kb ? pk1[0] : pk0[0];
      const bf16x4 q1 = kb ? pk1[1] : pk0[1];
      const bf16x4 q2 = kb ? pk1[2] : pk0[2];
      const bf16x4 q3 = kb ? pk1[3] : pk0[3];
      U ua;
      ua.v = hi ? q0 : q1;             // hi0 sends g1, hi1 sends g0
      U ra;
      ra.ll = __shfl_xor(ua.ll, 32);   // hi0 recv partner g0; hi1 recv g1
      U ub;
      ub.v = hi ? q2 : q3;             // hi0 sends g3, hi1 sends g2
      U rb;
      rb.ll = __shfl_xor(ub.ll, 32);   // hi0 recv partner g2; hi1 recv g3
      const bf16x4 lo0 = hi ? ra.v : q0;
      const bf16x4 hi0v = hi ? q1 : ra.v;
      const bf16x4 lo1 = hi ? rb.v : q2;
      const bf16x4 hi1v = hi ? q3 : rb.v;
      bf16x8 f0, f1;
#pragma unroll
      for (int j = 0; j < 4; ++j) {
        f0[j] = lo0[j];
        f0[4 + j] = hi0v[j];
        f1[j] = lo1[j];
        f1[4 + j] = hi1v[j];
      }
      pfr[kb * 2 + 0] = f0;
      pfr[kb * 2 + 1] = f1;
    }

    // PV: O^T += mfma32(V^T, P^T) — A=V^T (rows=d), B=P^T (cols=q).
    __builtin_amdgcn_s_setprio(1);
#pragma unroll
    for (int kdt = 0; kdt < 4; ++kdt) {
      const int c = (kdt * 16 + hi * 8);
      bf16x8 v0 = *(const bf16x8*)&Vt[l31 * 72 + (c ^ swz8(l31))];
      bf16x8 v1 = *(const bf16x8*)&Vt[(32 + l31) * 72 + (c ^ swz8(32 + l31))];
      Of0 = MFMA32(v0, pfr[kdt], Of0);
      Of1 = MFMA32(v1, pfr[kdt], Of1);
    }
    __builtin_amdgcn_s_setprio(0);
  }

  // epilogue: O^T lane holds d-chunks {8g+4hi..+3} of its own q-row;
  // 8B-contiguous stores, both hi lanes cover complementary d.
  const float inv = 1.0f / lrow;
  bf16_t* op = base + (size_t)(qlo + l31) * C3 + h * 64;
#pragma unroll
  for (int g = 0; g < 4; ++g) {
    bf16x4 o0, o1;
#pragma unroll
    for (int j = 0; j < 4; ++j) {
      o0[j] = (bf16_t)(Of0[4 * g + j] * inv);
      o1[j] = (bf16_t)(Of1[4 * g + j] * inv);
    }
    *(bf16x4*)&op[8 * g + 4 * hi] = o0;
    *(bf16x4*)&op[32 + 8 * g + 4 * hi] = o1;
  }
}

// ---------------------------------------------------------------------------
// I/O contract (R8 probe): ALL inputs f32; output f32.
// ---------------------------------------------------------------------------
extern "C" void kernel_launch(void* const* d_in, const int* in_sizes, int n_in,
                              void* d_out, int out_size, void* d_ws,
                              size_t ws_size, hipStream_t stream) {
  constexpr int B = 4, T = 2048, C = 1024;
  constexpr int M = B * T;  // 8192

  const float* x = (const float*)d_in[0];
  const float* w_qkv = (const float*)d_in[1];
  const float* w_out = (const float*)d_in[2];
  const float* b_out = (const float*)d_in[3];
  for (int i = 0; i < n_in; ++i) {
    const long long s = in_sizes[i];
    if (s == (long long)M * C) x = (const float*)d_in[i];
    else if (s == (long long)3 * C * C) w_qkv = (const float*)d_in[i];
    else if (s == (long long)C * C) w_out = (const float*)d_in[i];
    else if (s == C) b_out = (const float*)d_in[i];
  }

  bf16_t* xb = (bf16_t*)d_out;                    // 16 MB
  bf16_t* wqb = xb + (size_t)M * C;               // 6 MB
  bf16_t* qkv = (bf16_t*)d_ws;                    // 48 MB
  bf16_t* wob = qkv + (size_t)M * 3 * C;          // +2 MB (guarded)
  const bool ws_ok =
      ws_size >= (size_t)M * 3 * C * 2 + (size_t)C * C * 2;

  cvt3_f32_bf16<<<1024, 256, 0, stream>>>(
      x, xb, (long long)M * C, w_qkv, wqb, 3LL * C * C, w_out,
      ws_ok ? wob : nullptr, (long long)C * C);

  // fused QKV: [M,3C] = xb @ wqb^T
  gemm_async<false, bf16_t, false>
      <<<dim3(3 * C / 128, M / 128), 256, 0, stream>>>(
          xb, C, wqb, nullptr, qkv, 3 * C, M, 3 * C, C);

  // attention in place (Q slot of qkv); one strip per block, 4 blocks/CU
  attn_mfma<<<dim3(B * 16, 16), 256, 0, stream>>>(qkv);

  // out = att @ w_out^T + b_out -> f32 d_out
  if (ws_ok)
    gemm_async<false, float, true><<<dim3(C / 128, M / 128), 256, 0, stream>>>(
        qkv, 3 * C, wob, b_out, (float*)d_out, C, M, C, C);
  else
    gemm_async<true, float, true><<<dim3(C / 128, M / 128), 256, 0, stream>>>(
        qkv, 3 * C, w_out, b_out, (float*)d_out, C, M, C, C);
}